// Round 7
// baseline (131.445 us; speedup 1.0000x reference)
//
#include <hip/hip_runtime.h>
#include <hip/hip_bf16.h>

#define LOG2PI 1.8378770664093453f

// N=16384, M(K-dim)=4096, K(latent)=64.
// GEMM: Out[n][c] = sum_m x[n][m] * Bcat[c][m], staged cols c in [0,160) (144 real):
//   c 0-63: W_enc_mu col, 64-127: W_dec_mu row (c-64), 128: W_enc_sigma, 129: b_dec_mu.
// Split-K: KSPLIT slices of m; partials Pp[row][ks][144] (stride ppstride).
// col 130 of each partial = per-slice sum(x^2); cols 131-143 zero.
//
// Bp layout: per k-tile kt (64 m-values, 64 tiles), a 20480-B linear LDS image:
//   offset col*128 + u*16 (u in [0,8)) holds Bcat[col][kt*64 + (u^(col&7))*8 .. +8] bf16x8.
// A LDS image per step: row*256 + u*16 (u in [0,16)) holds
//   x[row][t*64 + (u^(row&15))*4 .. +4] fp32.

typedef __attribute__((ext_vector_type(8))) short bf16x8;
typedef __attribute__((ext_vector_type(4))) float f32x4;

__device__ __forceinline__ unsigned short f2bf(float f) {
    unsigned int u = __builtin_bit_cast(unsigned int, f);
    u += 0x7FFFu + ((u >> 16) & 1u);
    return (unsigned short)(u >> 16);
}
__device__ __forceinline__ short f2bf_s(float f) {
    return (short)__builtin_bit_cast(unsigned short, __float2bfloat16(f));
}
__device__ __forceinline__ void gll16(const void* g, void* l) {
    __builtin_amdgcn_global_load_lds(
        (const __attribute__((address_space(1))) void*)g,
        (__attribute__((address_space(3))) void*)l, 16, 0, 0);
}

// ---------------- pack B: per-64-k-tile linear LDS images (coalesced loads)
__global__ __launch_bounds__(256) void pack_b_kernel(const float* __restrict__ We,
        const float* __restrict__ Wes, const float* __restrict__ Wd,
        const float* __restrict__ bd, unsigned char* __restrict__ Bp) {
    __shared__ float WeL[4096];   // [64 m][64 c]
    __shared__ float WdL[4096];   // [64 r][64 m]
    __shared__ float WesL[64], bdL[64];
    const int kt = blockIdx.x;    // [0,64)
    const int t = threadIdx.x;
#pragma unroll
    for (int i = 0; i < 4; ++i) { // We slab: 16 KB contiguous
        int q = t + 256 * i;
        *reinterpret_cast<f32x4*>(WeL + q * 4) =
            *reinterpret_cast<const f32x4*>(We + (size_t)kt * 4096 + q * 4);
    }
#pragma unroll
    for (int i = 0; i < 4; ++i) { // Wd slab: 64 rows x 256 B
        int f = t + 256 * i;
        int r = f >> 4, s4 = f & 15;
        *reinterpret_cast<f32x4*>(WdL + r * 64 + s4 * 4) =
            *reinterpret_cast<const f32x4*>(Wd + (size_t)r * 4096 + kt * 64 + s4 * 4);
    }
    if (t < 16) {
        *reinterpret_cast<f32x4*>(WesL + t * 4) =
            *reinterpret_cast<const f32x4*>(Wes + kt * 64 + t * 4);
    } else if (t < 32) {
        int q = t - 16;
        *reinterpret_cast<f32x4*>(bdL + q * 4) =
            *reinterpret_cast<const f32x4*>(bd + kt * 64 + q * 4);
    }
    __syncthreads();
#pragma unroll
    for (int i = 0; i < 5; ++i) {
        int cidx = t + 256 * i;            // [0,1280) = col*8 + u
        int col = cidx >> 3, u = cidx & 7;
        int ku = u ^ (col & 7);
        unsigned short out[8];
#pragma unroll
        for (int j = 0; j < 8; ++j) {
            int m = ku * 8 + j;
            float v = 0.f;
            if (col < 64)        v = WeL[m * 64 + col];
            else if (col < 128)  v = WdL[(col - 64) * 64 + m];
            else if (col == 128) v = WesL[m];
            else if (col == 129) v = bdL[m];
            out[j] = f2bf(v);
        }
        *reinterpret_cast<uint4*>(Bp + ((size_t)kt * 1280 + cidx) * 16) =
            *reinterpret_cast<uint4*>(out);
    }
}

// ---------------- prep (coalesced): G pairs + h + e via row-dot blocks
__global__ __launch_bounds__(256) void prep_g_kernel(const float* __restrict__ Wd,
        const float* __restrict__ bd, float* __restrict__ G,
        float* __restrict__ hv, float* __restrict__ ev) {
    __shared__ float red[256];
    const int b = blockIdx.x, t = threadIdx.x;
    float p = 0.f;
    if (b < 4096) {
        int a = b >> 6, c = b & 63;
        const f32x4* ra = reinterpret_cast<const f32x4*>(Wd + (size_t)a * 4096);
        const f32x4* rc = reinterpret_cast<const f32x4*>(Wd + (size_t)c * 4096);
        for (int j = t; j < 1024; j += 256) {
            f32x4 u = ra[j], v = rc[j];
            p += u[0] * v[0] + u[1] * v[1] + u[2] * v[2] + u[3] * v[3];
        }
    } else if (b < 4160) {
        int a = b - 4096;
        const f32x4* ra = reinterpret_cast<const f32x4*>(Wd + (size_t)a * 4096);
        const f32x4* rb = reinterpret_cast<const f32x4*>(bd);
        for (int j = t; j < 1024; j += 256) {
            f32x4 u = ra[j], v = rb[j];
            p += u[0] * v[0] + u[1] * v[1] + u[2] * v[2] + u[3] * v[3];
        }
    } else {
        const f32x4* rb = reinterpret_cast<const f32x4*>(bd);
        for (int j = t; j < 1024; j += 256) {
            f32x4 v = rb[j];
            p += v[0] * v[0] + v[1] * v[1] + v[2] * v[2] + v[3] * v[3];
        }
    }
    red[t] = p;
    __syncthreads();
    for (int s = 128; s > 0; s >>= 1) { if (t < s) red[t] += red[t + s]; __syncthreads(); }
    if (t == 0) {
        if (b < 4096) G[b] = red[0];
        else if (b < 4160) hv[b - 4096] = red[0];
        else ev[0] = red[0];
    }
}

// ---------------- main GEMM: BK=64, one barrier per step, 2 blocks/CU
__global__ __launch_bounds__(256, 2) void gemm_kernel(const float* __restrict__ x,
        const unsigned char* __restrict__ Bp, float* __restrict__ Pp,
        int steps, int kslice, int ppstride) {
    __shared__ __align__(16) char lds[73728];    // 2 bufs x (A 16384 + B 20480)
    const int tid = threadIdx.x;
    const int lane = tid & 63, w = tid >> 6;
    const int wm = w >> 1, wn = w & 1;           // 2m x 2n waves
    const int l15 = lane & 15, kg = lane >> 4;
    const int rowbase = blockIdx.x * 64;
    const int ks = blockIdx.y;

    // A staging: 4 instrs/thread; instr i covers rows w*16+i*4 + (lane>>4)
    const float* xA[4];
#pragma unroll
    for (int i = 0; i < 4; ++i) {
        int rloc = w * 16 + i * 4 + (lane >> 4);
        int co = ((lane & 15) ^ (rloc & 15)) << 2;
        xA[i] = x + (size_t)(rowbase + rloc) * 4096 + (size_t)ks * kslice + co;
    }
    // B staging: 5 instrs/thread; linear copy of the pre-swizzled image
    const unsigned char* gB0 = Bp + (size_t)(w * 5) * 1024 + (size_t)lane * 16;
    const int ldsAoff = (w * 16) * 256 + lane * 16;
    const int ldsBoff = (w * 5) * 1024 + lane * 16;

    f32x4 acc[2][5];
#pragma unroll
    for (int mi = 0; mi < 2; ++mi)
#pragma unroll
        for (int ni = 0; ni < 5; ++ni) acc[mi][ni] = (f32x4){0.f, 0.f, 0.f, 0.f};
    float sxa0 = 0.f, sxa1 = 0.f;

#define STAGE(buf, tt) do { \
        _Pragma("unroll") \
        for (int i_ = 0; i_ < 4; ++i_) \
            gll16(xA[i_] + (tt) * 64, lds + (buf) * 36864 + ldsAoff + i_ * 1024); \
        _Pragma("unroll") \
        for (int j_ = 0; j_ < 5; ++j_) \
            gll16(gB0 + (size_t)(ks * steps + (tt)) * 20480 + j_ * 1024, \
                  lds + (buf) * 36864 + 16384 + ldsBoff + j_ * 1024); \
    } while (0)

#define COMPUTE(buf) do { \
        char* A0 = lds + (buf) * 36864; \
        char* B0 = A0 + 16384; \
        _Pragma("unroll") \
        for (int kk_ = 0; kk_ < 2; ++kk_) { \
            bf16x8 bfr[5]; \
            _Pragma("unroll") \
            for (int ni_ = 0; ni_ < 5; ++ni_) { \
                int col_ = wn * 80 + ni_ * 16 + l15; \
                bfr[ni_] = *reinterpret_cast<const bf16x8*>( \
                    B0 + col_ * 128 + (((kk_ * 4 + kg) ^ (col_ & 7)) << 4)); \
            } \
            _Pragma("unroll") \
            for (int mi_ = 0; mi_ < 2; ++mi_) { \
                int row_ = wm * 32 + mi_ * 16 + l15; \
                int u0_ = kk_ * 8 + kg * 2; \
                f32x4 fa_ = *reinterpret_cast<const f32x4*>( \
                    A0 + row_ * 256 + (((u0_) ^ (row_ & 15)) << 4)); \
                f32x4 fb_ = *reinterpret_cast<const f32x4*>( \
                    A0 + row_ * 256 + (((u0_ + 1) ^ (row_ & 15)) << 4)); \
                bf16x8 af_; \
                af_[0] = f2bf_s(fa_[0]); af_[1] = f2bf_s(fa_[1]); \
                af_[2] = f2bf_s(fa_[2]); af_[3] = f2bf_s(fa_[3]); \
                af_[4] = f2bf_s(fb_[0]); af_[5] = f2bf_s(fb_[1]); \
                af_[6] = f2bf_s(fb_[2]); af_[7] = f2bf_s(fb_[3]); \
                if (wn == 0) { \
                    float ss_ = fa_[0]*fa_[0] + fa_[1]*fa_[1] + fa_[2]*fa_[2] + fa_[3]*fa_[3] \
                              + fb_[0]*fb_[0] + fb_[1]*fb_[1] + fb_[2]*fb_[2] + fb_[3]*fb_[3]; \
                    if (mi_ == 0) sxa0 += ss_; else sxa1 += ss_; \
                } \
                _Pragma("unroll") \
                for (int ni_ = 0; ni_ < 5; ++ni_) \
                    acc[mi_][ni_] = __builtin_amdgcn_mfma_f32_16x16x32_bf16( \
                        af_, bfr[ni_], acc[mi_][ni_], 0, 0, 0); \
            } \
        } \
    } while (0)

    STAGE(0, 0);
    asm volatile("s_waitcnt vmcnt(0)" ::: "memory");
    __builtin_amdgcn_s_barrier();
    asm volatile("" ::: "memory");
    int cur = 0;
    for (int t = 0; t < steps; ++t) {
        if (t + 1 < steps) STAGE(cur ^ 1, t + 1);   // into the buffer everyone freed
        COMPUTE(cur);
        asm volatile("s_waitcnt vmcnt(0)" ::: "memory");
        __builtin_amdgcn_s_barrier();
        asm volatile("" ::: "memory");
        cur ^= 1;
    }
#undef STAGE
#undef COMPUTE

    // reduce sx2 across kg groups (lanes 0-15 end with row totals)
    sxa0 += __shfl_xor(sxa0, 16); sxa0 += __shfl_xor(sxa0, 32);
    sxa1 += __shfl_xor(sxa1, 16); sxa1 += __shfl_xor(sxa1, 32);

    // ---- coalesced writeback: acc -> LDS C-tile [64][148], then full rows out
    __syncthreads();
    float* C = reinterpret_cast<float*>(lds);
#pragma unroll
    for (int mi = 0; mi < 2; ++mi)
#pragma unroll
        for (int ni = 0; ni < 5; ++ni) {
            int col = wn * 80 + ni * 16 + l15;
            if (col < 148 && col != 130) {
#pragma unroll
                for (int i2 = 0; i2 < 4; ++i2)
                    C[(wm * 32 + mi * 16 + kg * 4 + i2) * 148 + col] = acc[mi][ni][i2];
            }
        }
    if (wn == 0 && lane < 16) {
        C[(wm * 32 + lane) * 148 + 130] = sxa0;
        C[(wm * 32 + 16 + lane) * 148 + 130] = sxa1;
    }
    __syncthreads();
#pragma unroll
    for (int i = 0; i < 9; ++i) {
        int idx = tid + 256 * i;
        int r = idx / 36, c4 = idx % 36;
        f32x4 v = *reinterpret_cast<const f32x4*>(C + r * 148 + c4 * 4);
        *reinterpret_cast<f32x4*>(Pp + (size_t)(rowbase + r) * ppstride + ks * 144 + c4 * 4) = v;
    }
}

// ---------------- phase 2: plain [64][64] G, XOR-permuted conflict-free matvec
__global__ __launch_bounds__(256) void phase2_kernel(const float* __restrict__ Pp,
        const float* __restrict__ noise, const float* __restrict__ bem,
        const float* __restrict__ Wds, const float* __restrict__ bes_p,
        const float* __restrict__ bds_p, const float* __restrict__ G,
        const float* __restrict__ hv, const float* __restrict__ ev,
        float* __restrict__ partial, int ksplit, int ppstride) {
    __shared__ float Gl[4096];
    __shared__ float hl[64], wl[64], beml[64];
    __shared__ float zs[4][64];
    __shared__ float red[4];
    int tid = threadIdx.x;
    for (int i = tid; i < 4096; i += 256) Gl[i] = G[i];
    if (tid < 64) { hl[tid] = hv[tid]; wl[tid] = Wds[tid]; beml[tid] = bem[tid]; }
    __syncthreads();
    float bes = bes_p[0], bds = bds_p[0], e = ev[0];
    int wid = tid >> 6, k = tid & 63;
    const int sw = (k & 15) << 2;
    float wacc = 0.f;
#pragma unroll
    for (int rr = 0; rr < 8; ++rr) {
        int row = blockIdx.x * 32 + wid * 8 + rr;
        const float* base = Pp + (size_t)row * ppstride;
        float zmu = beml[k], ck = 0.f, se = bes, dd = 0.f, sx2 = 0.f;
        for (int s = 0; s < ksplit; ++s) {
            const float* b2 = base + s * 144;
            zmu += b2[k]; ck += b2[64 + k];
            se += b2[128]; dd += b2[129]; sx2 += b2[130];
        }
        float nz = noise[(size_t)row * 64 + k];
        float s2 = se * se;
        float z = fmaf(s2, nz, zmu);
        zs[wid][k] = z;
        float t0 = 0.f, t1 = 0.f, t2 = 0.f, t3 = 0.f;
        const float* gr = &Gl[k * 64];
        const float* zr = &zs[wid][0];
#pragma unroll
        for (int jb = 0; jb < 16; ++jb) {
            int p = (jb * 4) ^ sw;
            f32x4 gv = *reinterpret_cast<const f32x4*>(gr + p);
            f32x4 zv = *reinterpret_cast<const f32x4*>(zr + p);
            t0 = fmaf(gv[0], zv[0], t0); t1 = fmaf(gv[1], zv[1], t1);
            t2 = fmaf(gv[2], zv[2], t2); t3 = fmaf(gv[3], zv[3], t3);
        }
        float t = (t0 + t1) + (t2 + t3);
        float ra = z * z;
        float rb = nz * nz;
        float rc = z * wl[k];
        float rd = z * ck;
        float re = z * fmaf(2.f, hl[k], t);
#pragma unroll
        for (int d = 1; d < 64; d <<= 1) {
            ra += __shfl_xor(ra, d); rb += __shfl_xor(rb, d);
            rc += __shfl_xor(rc, d); rd += __shfl_xor(rd, d);
            re += __shfl_xor(re, d);
        }
        float sdec = rc + bds;
        float xxmu = rd + dd;
        float xmu2 = re + e;
        float sq_lik = sx2 - 2.f * xxmu + xmu2;
        float vz = s2 * s2;
        float sd2 = sdec * sdec;
        float vx = sd2 * sd2;
        wacc += 0.5f * (4096.f * LOG2PI + 4096.f * __logf(vx) + sq_lik / vx
                        + ra - 64.f * __logf(vz) - rb);
    }
    if (k == 0) red[wid] = wacc;
    __syncthreads();
    if (tid == 0) partial[blockIdx.x] = red[0] + red[1] + red[2] + red[3];
}

__global__ __launch_bounds__(256) void final_reduce_kernel(const float* __restrict__ partial,
                                                           float* __restrict__ out) {
    __shared__ float red[4];
    int tid = threadIdx.x;
    float v = 0.f;
    for (int i = tid; i < 512; i += 256) v += partial[i];
#pragma unroll
    for (int d = 1; d < 64; d <<= 1) v += __shfl_xor(v, d);
    if ((tid & 63) == 0) red[tid >> 6] = v;
    __syncthreads();
    if (tid == 0) out[0] = red[0] + red[1] + red[2] + red[3];
}

extern "C" void kernel_launch(void* const* d_in, const int* in_sizes, int n_in,
                              void* d_out, int out_size, void* d_ws, size_t ws_size,
                              hipStream_t stream) {
    const float* x     = (const float*)d_in[0];
    const float* noise = (const float*)d_in[1];
    const float* We    = (const float*)d_in[2];
    const float* bem   = (const float*)d_in[3];
    const float* Wes   = (const float*)d_in[4];
    const float* bes   = (const float*)d_in[5];
    const float* Wd    = (const float*)d_in[6];
    const float* bdm   = (const float*)d_in[7];
    const float* Wds   = (const float*)d_in[8];
    const float* bds   = (const float*)d_in[9];

    int ksplit = (ws_size >= 39340544ull) ? 4 : (ws_size >= 20466176ull ? 2 : 1);
    int steps = 64 / ksplit;          // BK=64 tiles per k-slice
    int kslice = steps * 64;
    int ppstride = ksplit * 144;

    char* ws = (char*)d_ws;
    size_t ppbytes = (size_t)16384 * ppstride * 4;
    float* Pp           = (float*)ws;
    unsigned char* Bp   = (unsigned char*)(ws + ppbytes);   // 1,310,720 B used
    float* G            = (float*)(ws + ppbytes + 1572864);
    float* hv           = (float*)(ws + ppbytes + 1572864 + 16384);
    float* ev           = (float*)(ws + ppbytes + 1572864 + 16640);
    float* partial      = (float*)(ws + ppbytes + 1572864 + 16896);

    pack_b_kernel<<<64, 256, 0, stream>>>(We, Wes, Wd, bdm, Bp);
    prep_g_kernel<<<4161, 256, 0, stream>>>(Wd, bdm, G, hv, ev);
    gemm_kernel<<<dim3(256, ksplit), 256, 0, stream>>>(x, Bp, Pp, steps, kslice, ppstride);
    phase2_kernel<<<512, 256, 0, stream>>>(Pp, noise, bem, Wds, bes, bds, G, hv, ev,
                                           partial, ksplit, ppstride);
    final_reduce_kernel<<<1, 256, 0, stream>>>(partial, (float*)d_out);
}

// Round 8
// 116.556 us; speedup vs baseline: 1.1277x; 1.1277x over previous
//
#include <hip/hip_runtime.h>
#include <hip/hip_bf16.h>

#define LOG2PI 1.8378770664093453f

// N=16384, M(K-dim)=4096, K(latent)=64.
// GEMM: Out[n][c] = sum_m x[n][m] * Bcat[c][m], staged cols c in [0,192) (144 real):
//   c 0-63: W_enc_mu col, 64-127: W_dec_mu row (c-64), 128: W_enc_sigma, 129: b_dec_mu.
// Split-K: KSPLIT slices of m; partials Pp[row][ks][144] (stride ppstride).
// col 130 of each partial = per-slice sum(x^2); cols 131-143 zero.
//
// Bp layout: per k-tile kt (32 m-values, 128 tiles), a 12288-B linear LDS image:
//   offset col*64 + u*16 holds Bcat[col][kt*32 + (u^q(col))*8 .. +8] as 8 bf16,
//   q(col) = (col + (col>>2)) & 3  (gives 2-way-free ds_read banking).
// A LDS image per step: row*128 + u8*16 holds x[row][t*32 + (u8^(row&7))*4 ..+4] fp32.
// BM=128 rows/block, BK=32, 4 waves (2m x 2n), 2 blocks/CU.

typedef __attribute__((ext_vector_type(8))) short bf16x8;
typedef __attribute__((ext_vector_type(4))) float f32x4;

__device__ __forceinline__ unsigned short f2bf(float f) {
    unsigned int u = __builtin_bit_cast(unsigned int, f);
    u += 0x7FFFu + ((u >> 16) & 1u);
    return (unsigned short)(u >> 16);
}
__device__ __forceinline__ short f2bf_s(float f) {
    return (short)__builtin_bit_cast(unsigned short, __float2bfloat16(f));
}
__device__ __forceinline__ void gll16(const void* g, void* l) {
    __builtin_amdgcn_global_load_lds(
        (const __attribute__((address_space(1))) void*)g,
        (__attribute__((address_space(3))) void*)l, 16, 0, 0);
}

// ---------------- pack B (coalesced): one block per k-tile of 32 m-values
__global__ __launch_bounds__(256) void pack_b_kernel(const float* __restrict__ We,
        const float* __restrict__ Wes, const float* __restrict__ Wd,
        const float* __restrict__ bd, unsigned char* __restrict__ Bp) {
    __shared__ float WeL[2048];   // [32 m][64 c]
    __shared__ float WdL[2048];   // [64 r][32 m]
    __shared__ float WesL[32], bdL[32];
    const int kt = blockIdx.x;    // [0,128)
    const int t = threadIdx.x;
#pragma unroll
    for (int i = 0; i < 2; ++i) {
        int q = t + 256 * i;
        *reinterpret_cast<f32x4*>(WeL + q * 4) =
            *reinterpret_cast<const f32x4*>(We + (size_t)kt * 2048 + q * 4);
    }
#pragma unroll
    for (int i = 0; i < 2; ++i) {
        int f = t + 256 * i;
        int r = f >> 3, s4 = f & 7;
        *reinterpret_cast<f32x4*>(WdL + r * 32 + s4 * 4) =
            *reinterpret_cast<const f32x4*>(Wd + (size_t)r * 4096 + kt * 32 + s4 * 4);
    }
    if (t < 8) {
        *reinterpret_cast<f32x4*>(WesL + t * 4) =
            *reinterpret_cast<const f32x4*>(Wes + kt * 32 + t * 4);
    } else if (t < 16) {
        int q = t - 8;
        *reinterpret_cast<f32x4*>(bdL + q * 4) =
            *reinterpret_cast<const f32x4*>(bd + kt * 32 + q * 4);
    }
    __syncthreads();
#pragma unroll
    for (int i = 0; i < 3; ++i) {
        int cidx = t + 256 * i;            // [0,768) = col*4 + u
        int col = cidx >> 2, u = cidx & 3;
        int ku = u ^ ((col + (col >> 2)) & 3);
        unsigned short out[8];
#pragma unroll
        for (int j = 0; j < 8; ++j) {
            int ml = ku * 8 + j;
            float v = 0.f;
            if (col < 64)        v = WeL[ml * 64 + col];
            else if (col < 128)  v = WdL[(col - 64) * 32 + ml];
            else if (col == 128) v = WesL[ml];
            else if (col == 129) v = bdL[ml];
            out[j] = f2bf(v);
        }
        *reinterpret_cast<uint4*>(Bp + ((size_t)kt * 768 + cidx) * 16) =
            *reinterpret_cast<uint4*>(out);
    }
}

// ---------------- prep (coalesced): G pairs + h + e via row-dot blocks
__global__ __launch_bounds__(256) void prep_g_kernel(const float* __restrict__ Wd,
        const float* __restrict__ bd, float* __restrict__ G,
        float* __restrict__ hv, float* __restrict__ ev) {
    __shared__ float red[256];
    const int b = blockIdx.x, t = threadIdx.x;
    float p = 0.f;
    if (b < 4096) {
        int a = b >> 6, c = b & 63;
        const f32x4* ra = reinterpret_cast<const f32x4*>(Wd + (size_t)a * 4096);
        const f32x4* rc = reinterpret_cast<const f32x4*>(Wd + (size_t)c * 4096);
        for (int j = t; j < 1024; j += 256) {
            f32x4 u = ra[j], v = rc[j];
            p += u[0] * v[0] + u[1] * v[1] + u[2] * v[2] + u[3] * v[3];
        }
    } else if (b < 4160) {
        int a = b - 4096;
        const f32x4* ra = reinterpret_cast<const f32x4*>(Wd + (size_t)a * 4096);
        const f32x4* rb = reinterpret_cast<const f32x4*>(bd);
        for (int j = t; j < 1024; j += 256) {
            f32x4 u = ra[j], v = rb[j];
            p += u[0] * v[0] + u[1] * v[1] + u[2] * v[2] + u[3] * v[3];
        }
    } else {
        const f32x4* rb = reinterpret_cast<const f32x4*>(bd);
        for (int j = t; j < 1024; j += 256) {
            f32x4 v = rb[j];
            p += v[0] * v[0] + v[1] * v[1] + v[2] * v[2] + v[3] * v[3];
        }
    }
    red[t] = p;
    __syncthreads();
    for (int s = 128; s > 0; s >>= 1) { if (t < s) red[t] += red[t + s]; __syncthreads(); }
    if (t == 0) {
        if (b < 4096) G[b] = red[0];
        else if (b < 4160) hv[b - 4096] = red[0];
        else ev[0] = red[0];
    }
}

// ---------------- main GEMM: BM=128, BK=32, R6 pipeline (counted vmcnt(7))
__global__ __launch_bounds__(256, 2) void gemm_kernel(const float* __restrict__ x,
        const unsigned char* __restrict__ Bp, float* __restrict__ Pp,
        int steps, int kslice, int ppstride) {
    __shared__ __align__(16) char lds[57344];    // 2 bufs x (A 16384 + B 12288)
    const int tid = threadIdx.x;
    const int lane = tid & 63, w = tid >> 6;
    const int wm = w >> 1, wn = w & 1;           // 2m x 2n waves, wave owns 64x80
    const int l15 = lane & 15, kg = lane >> 4;
    const int rowbase = blockIdx.x * 128;
    const int ks = blockIdx.y;

    // A staging: 4 instrs/thread; instr i -> linear chunk q = i*256+tid
    const float* xA[4];
#pragma unroll
    for (int i = 0; i < 4; ++i) {
        int q = i * 256 + tid;
        int row = q >> 3, u8 = q & 7;
        int co = (u8 ^ (row & 7)) << 2;
        xA[i] = x + (size_t)(rowbase + row) * 4096 + (size_t)ks * kslice + co;
    }
    // B staging: 3 instrs/thread; linear copy of pre-swizzled image
    const unsigned char* gB0 = Bp + (size_t)tid * 16;

    f32x4 acc[4][5];
#pragma unroll
    for (int mi = 0; mi < 4; ++mi)
#pragma unroll
        for (int ni = 0; ni < 5; ++ni) acc[mi][ni] = (f32x4){0.f, 0.f, 0.f, 0.f};
    float sxa[4] = {0.f, 0.f, 0.f, 0.f};

#define STAGE(buf, tt) do { \
        _Pragma("unroll") \
        for (int i_ = 0; i_ < 4; ++i_) \
            gll16(xA[i_] + (tt) * 32, lds + (buf) * 28672 + i_ * 4096 + tid * 16); \
        _Pragma("unroll") \
        for (int j_ = 0; j_ < 3; ++j_) \
            gll16(gB0 + (size_t)(ks * steps + (tt)) * 12288 + j_ * 4096, \
                  lds + (buf) * 28672 + 16384 + j_ * 4096 + tid * 16); \
    } while (0)

#define COMPUTE(buf) do { \
        char* A0 = lds + (buf) * 28672; \
        char* B0 = A0 + 16384; \
        bf16x8 bfr[5]; \
        _Pragma("unroll") \
        for (int ni_ = 0; ni_ < 5; ++ni_) { \
            int col_ = wn * 80 + ni_ * 16 + l15; \
            int q_ = (col_ + (col_ >> 2)) & 3; \
            bfr[ni_] = *reinterpret_cast<const bf16x8*>( \
                B0 + col_ * 64 + ((kg ^ q_) << 4)); \
        } \
        _Pragma("unroll") \
        for (int mi_ = 0; mi_ < 4; ++mi_) { \
            int row_ = wm * 64 + mi_ * 16 + l15; \
            int e0_ = (kg << 1) ^ (row_ & 7); \
            f32x4 fa_ = *reinterpret_cast<const f32x4*>(A0 + row_ * 128 + (e0_ << 4)); \
            f32x4 fb_ = *reinterpret_cast<const f32x4*>(A0 + row_ * 128 + ((e0_ ^ 1) << 4)); \
            bf16x8 af_; \
            af_[0] = f2bf_s(fa_[0]); af_[1] = f2bf_s(fa_[1]); \
            af_[2] = f2bf_s(fa_[2]); af_[3] = f2bf_s(fa_[3]); \
            af_[4] = f2bf_s(fb_[0]); af_[5] = f2bf_s(fb_[1]); \
            af_[6] = f2bf_s(fb_[2]); af_[7] = f2bf_s(fb_[3]); \
            if (wn == 0) { \
                sxa[mi_] += fa_[0]*fa_[0] + fa_[1]*fa_[1] + fa_[2]*fa_[2] + fa_[3]*fa_[3] \
                          + fb_[0]*fb_[0] + fb_[1]*fb_[1] + fb_[2]*fb_[2] + fb_[3]*fb_[3]; \
            } \
            _Pragma("unroll") \
            for (int ni_ = 0; ni_ < 5; ++ni_) \
                acc[mi_][ni_] = __builtin_amdgcn_mfma_f32_16x16x32_bf16( \
                    af_, bfr[ni_], acc[mi_][ni_], 0, 0, 0); \
        } \
    } while (0)

    STAGE(0, 0);
    asm volatile("s_waitcnt vmcnt(0)" ::: "memory");
    __builtin_amdgcn_s_barrier();
    asm volatile("" ::: "memory");
    int cur = 0;
    for (int t = 0; t < steps - 1; ++t) {
        STAGE(cur ^ 1, t + 1);
        asm volatile("s_waitcnt vmcnt(7)" ::: "memory");   // drains step-t loads only
        __builtin_amdgcn_s_barrier();
        asm volatile("" ::: "memory");
        COMPUTE(cur);
        asm volatile("" ::: "memory");
        __builtin_amdgcn_s_barrier();
        cur ^= 1;
    }
    asm volatile("s_waitcnt vmcnt(0)" ::: "memory");
    __builtin_amdgcn_s_barrier();
    asm volatile("" ::: "memory");
    COMPUTE(cur);
#undef STAGE
#undef COMPUTE

    // reduce sx2 across kg groups (lanes 0-15 end with full row sums)
#pragma unroll
    for (int mi = 0; mi < 4; ++mi) {
        sxa[mi] += __shfl_xor(sxa[mi], 16);
        sxa[mi] += __shfl_xor(sxa[mi], 32);
    }

    // ---- coalesced writeback in two 64-row passes via LDS C-tile [64][148]
    float* C = reinterpret_cast<float*>(lds);
#pragma unroll
    for (int pass = 0; pass < 2; ++pass) {
        __syncthreads();
        if (wm == pass) {
#pragma unroll
            for (int mi = 0; mi < 4; ++mi)
#pragma unroll
                for (int ni = 0; ni < 5; ++ni) {
                    int col = wn * 80 + ni * 16 + l15;
                    if (col < 148 && col != 130) {
#pragma unroll
                        for (int i2 = 0; i2 < 4; ++i2)
                            C[(mi * 16 + kg * 4 + i2) * 148 + col] = acc[mi][ni][i2];
                    }
                }
            if (wn == 0 && lane < 16) {
#pragma unroll
                for (int mi = 0; mi < 4; ++mi)
                    C[(mi * 16 + lane) * 148 + 130] = sxa[mi];
            }
        }
        __syncthreads();
#pragma unroll
        for (int i = 0; i < 9; ++i) {
            int idx = tid + 256 * i;
            int r = idx / 36, c4 = idx % 36;
            f32x4 v = *reinterpret_cast<const f32x4*>(C + r * 148 + c4 * 4);
            *reinterpret_cast<f32x4*>(
                Pp + (size_t)(rowbase + pass * 64 + r) * ppstride + ks * 144 + c4 * 4) = v;
        }
    }
}

// ---------------- phase 2: plain [64][64] G, XOR-permuted conflict-free matvec
__global__ __launch_bounds__(256) void phase2_kernel(const float* __restrict__ Pp,
        const float* __restrict__ noise, const float* __restrict__ bem,
        const float* __restrict__ Wds, const float* __restrict__ bes_p,
        const float* __restrict__ bds_p, const float* __restrict__ G,
        const float* __restrict__ hv, const float* __restrict__ ev,
        float* __restrict__ partial, int ksplit, int ppstride) {
    __shared__ float Gl[4096];
    __shared__ float hl[64], wl[64], beml[64];
    __shared__ float zs[4][64];
    __shared__ float red[4];
    int tid = threadIdx.x;
    for (int i = tid; i < 4096; i += 256) Gl[i] = G[i];
    if (tid < 64) { hl[tid] = hv[tid]; wl[tid] = Wds[tid]; beml[tid] = bem[tid]; }
    __syncthreads();
    float bes = bes_p[0], bds = bds_p[0], e = ev[0];
    int wid = tid >> 6, k = tid & 63;
    const int sw = (k & 15) << 2;
    float wacc = 0.f;
#pragma unroll
    for (int rr = 0; rr < 8; ++rr) {
        int row = blockIdx.x * 32 + wid * 8 + rr;
        const float* base = Pp + (size_t)row * ppstride;
        float zmu = beml[k], ck = 0.f, se = bes, dd = 0.f, sx2 = 0.f;
        for (int s = 0; s < ksplit; ++s) {
            const float* b2 = base + s * 144;
            zmu += b2[k]; ck += b2[64 + k];
            se += b2[128]; dd += b2[129]; sx2 += b2[130];
        }
        float nz = noise[(size_t)row * 64 + k];
        float s2 = se * se;
        float z = fmaf(s2, nz, zmu);
        zs[wid][k] = z;
        float t0 = 0.f, t1 = 0.f, t2 = 0.f, t3 = 0.f;
        const float* gr = &Gl[k * 64];
        const float* zr = &zs[wid][0];
#pragma unroll
        for (int jb = 0; jb < 16; ++jb) {
            int p = (jb * 4) ^ sw;
            f32x4 gv = *reinterpret_cast<const f32x4*>(gr + p);
            f32x4 zv = *reinterpret_cast<const f32x4*>(zr + p);
            t0 = fmaf(gv[0], zv[0], t0); t1 = fmaf(gv[1], zv[1], t1);
            t2 = fmaf(gv[2], zv[2], t2); t3 = fmaf(gv[3], zv[3], t3);
        }
        float t = (t0 + t1) + (t2 + t3);
        float ra = z * z;
        float rb = nz * nz;
        float rc = z * wl[k];
        float rd = z * ck;
        float re = z * fmaf(2.f, hl[k], t);
#pragma unroll
        for (int d = 1; d < 64; d <<= 1) {
            ra += __shfl_xor(ra, d); rb += __shfl_xor(rb, d);
            rc += __shfl_xor(rc, d); rd += __shfl_xor(rd, d);
            re += __shfl_xor(re, d);
        }
        float sdec = rc + bds;
        float xxmu = rd + dd;
        float xmu2 = re + e;
        float sq_lik = sx2 - 2.f * xxmu + xmu2;
        float vz = s2 * s2;
        float sd2 = sdec * sdec;
        float vx = sd2 * sd2;
        wacc += 0.5f * (4096.f * LOG2PI + 4096.f * __logf(vx) + sq_lik / vx
                        + ra - 64.f * __logf(vz) - rb);
    }
    if (k == 0) red[wid] = wacc;
    __syncthreads();
    if (tid == 0) partial[blockIdx.x] = red[0] + red[1] + red[2] + red[3];
}

__global__ __launch_bounds__(256) void final_reduce_kernel(const float* __restrict__ partial,
                                                           float* __restrict__ out) {
    __shared__ float red[4];
    int tid = threadIdx.x;
    float v = 0.f;
    for (int i = tid; i < 512; i += 256) v += partial[i];
#pragma unroll
    for (int d = 1; d < 64; d <<= 1) v += __shfl_xor(v, d);
    if ((tid & 63) == 0) red[tid >> 6] = v;
    __syncthreads();
    if (tid == 0) out[0] = red[0] + red[1] + red[2] + red[3];
}

extern "C" void kernel_launch(void* const* d_in, const int* in_sizes, int n_in,
                              void* d_out, int out_size, void* d_ws, size_t ws_size,
                              hipStream_t stream) {
    const float* x     = (const float*)d_in[0];
    const float* noise = (const float*)d_in[1];
    const float* We    = (const float*)d_in[2];
    const float* bem   = (const float*)d_in[3];
    const float* Wes   = (const float*)d_in[4];
    const float* bes   = (const float*)d_in[5];
    const float* Wd    = (const float*)d_in[6];
    const float* bdm   = (const float*)d_in[7];
    const float* Wds   = (const float*)d_in[8];
    const float* bds   = (const float*)d_in[9];

    int ksplit = (ws_size >= 39340544ull) ? 4 : (ws_size >= 20466176ull ? 2 : 1);
    int steps = 128 / ksplit;         // BK=32 tiles per k-slice
    int kslice = steps * 32;
    int ppstride = ksplit * 144;

    char* ws = (char*)d_ws;
    size_t ppbytes = (size_t)16384 * ppstride * 4;
    float* Pp           = (float*)ws;
    unsigned char* Bp   = (unsigned char*)(ws + ppbytes);   // 1,572,864 B
    float* G            = (float*)(ws + ppbytes + 1572864);
    float* hv           = (float*)(ws + ppbytes + 1572864 + 16384);
    float* ev           = (float*)(ws + ppbytes + 1572864 + 16640);
    float* partial      = (float*)(ws + ppbytes + 1572864 + 16896);

    pack_b_kernel<<<128, 256, 0, stream>>>(We, Wes, Wd, bdm, Bp);
    prep_g_kernel<<<4161, 256, 0, stream>>>(Wd, bdm, G, hv, ev);
    gemm_kernel<<<dim3(128, ksplit), 256, 0, stream>>>(x, Bp, Pp, steps, kslice, ppstride);
    phase2_kernel<<<512, 256, 0, stream>>>(Pp, noise, bem, Wds, bes, bds, G, hv, ev,
                                           partial, ksplit, ppstride);
    final_reduce_kernel<<<1, 256, 0, stream>>>(partial, (float*)d_out);
}